// Round 1
// baseline (225.654 us; speedup 1.0000x reference)
//
#include <hip/hip_runtime.h>
#include <hip/hip_bf16.h>
#include <math.h>

// MHA with sequence-split heads: head h of batch b = contiguous rows [256h,256h+256)
// of the [2048,512] projection, viewed row-major as [2048,64].
// Pipeline: cvt->bf16, 3x proj GEMM (bf16 MFMA), V transpose, flash attn, out GEMM.

typedef float  f32x4 __attribute__((ext_vector_type(4)));
typedef short  s16x8 __attribute__((ext_vector_type(8)));

__device__ inline unsigned short f2b(float f){
  union { float f; unsigned int u; } c; c.f = f;
  unsigned int u = c.u;
  unsigned int r = (u + 0x7FFFu + ((u >> 16) & 1u)) >> 16;
  return (unsigned short)r;
}

__global__ __launch_bounds__(256) void cvt_f32_bf16(const float* __restrict__ src,
                                                    unsigned short* __restrict__ dst, int n){
  int i = (blockIdx.x * 256 + threadIdx.x) * 4;
  if (i + 3 < n){
    f32x4 v = *(const f32x4*)(src + i);
    dst[i+0] = f2b(v.x);
    dst[i+1] = f2b(v.y);
    dst[i+2] = f2b(v.z);
    dst[i+3] = f2b(v.w);
  }
}

// C = A[M,512] @ W[512cols,512k]^T + bias. A,W bf16 row-major (both K-contiguous).
// 64x64 tile per block, 4 waves, each wave 16 rows x 64 cols. Direct global frag loads.
template<int OUTF32>
__global__ __launch_bounds__(256) void gemm_bt(const unsigned short* __restrict__ A,
                                               const unsigned short* __restrict__ W,
                                               const float* __restrict__ bias,
                                               void* __restrict__ outp){
  int w = threadIdx.x >> 6, lane = threadIdx.x & 63;
  int lr = lane & 15, lg = lane >> 4;
  int arow = blockIdx.x * 64 + w * 16 + lr;
  int wrow0 = blockIdx.y * 64;
  f32x4 acc[4] = {};
  const unsigned short* Ap = A + arow * 512 + lg * 8;
#pragma unroll 4
  for (int ks = 0; ks < 512; ks += 32){
    s16x8 af = *(const s16x8*)(Ap + ks);
#pragma unroll
    for (int n = 0; n < 4; ++n){
      s16x8 bf = *(const s16x8*)(W + (wrow0 + n*16 + lr) * 512 + ks + lg * 8);
      acc[n] = __builtin_amdgcn_mfma_f32_16x16x32_bf16(af, bf, acc[n], 0, 0, 0);
    }
  }
  int orow = blockIdx.x * 64 + w * 16 + lg * 4;
#pragma unroll
  for (int n = 0; n < 4; ++n){
    int col = wrow0 + n * 16 + lr;
    float bv = bias[col];
#pragma unroll
    for (int r = 0; r < 4; ++r){
      float v = acc[n][r] + bv;
      if (OUTF32) ((float*)outp)[(size_t)(orow + r) * 512 + col] = v;
      else ((unsigned short*)outp)[(size_t)(orow + r) * 512 + col] = f2b(v);
    }
  }
}

// Vt[bh][d=64][key=2048] = V_h[key][d]
__global__ __launch_bounds__(256) void vtrans(const unsigned short* __restrict__ Pv,
                                              unsigned short* __restrict__ Vt){
  int kt = blockIdx.x, bh = blockIdx.y;
  int b = bh >> 3, h = bh & 7;
  __shared__ unsigned short t[64][65];
  const unsigned short* src = Pv + (b*2048 + h*256)*512 + kt*4096;
  for (int i = threadIdx.x; i < 4096; i += 256){ int r = i >> 6, c = i & 63; t[r][c] = src[i]; }
  __syncthreads();
  unsigned short* dst = Vt + bh*131072 + kt*64;
  for (int i = threadIdx.x; i < 4096; i += 256){ int d = i >> 6, kk = i & 63; dst[d*2048 + kk] = t[kk][d]; }
}

// Flash attention per (qtile, bh). 4 waves x 16 q-rows. Online softmax.
// MFMA 16x16x32: A frag row=lane&15, k=(lane>>4)*8+j ; B frag col=lane&15, k=(lane>>4)*8+j ;
// C frag col=lane&15, row=(lane>>4)*4+reg (verified layouts).
__global__ __launch_bounds__(256) void flash(const unsigned short* __restrict__ Pq,
                                             const unsigned short* __restrict__ Pk,
                                             const unsigned short* __restrict__ Vt,
                                             const unsigned char* __restrict__ mask,
                                             unsigned short* __restrict__ attnOut){
  int qt = blockIdx.x;          // 0..31
  int bh = blockIdx.y;          // 0..15
  int b = bh >> 3, h = bh & 7;
  int w = threadIdx.x >> 6, lane = threadIdx.x & 63;
  int lr = lane & 15, lg = lane >> 4;

  const unsigned short* Qh = Pq + (b*2048 + h*256)*512;   // [2048][64]
  const unsigned short* Kh = Pk + (b*2048 + h*256)*512;   // [2048][64]
  const unsigned short* Vth = Vt + bh*131072;             // [64][2048]
  const unsigned char* mrow = mask + b*2048;

  __shared__ unsigned short plds[4][16][72];              // per-wave P scratch, padded

  int qrow = qt*64 + w*16 + lr;
  s16x8 qf0 = *(const s16x8*)(Qh + qrow*64 + lg*8);
  s16x8 qf1 = *(const s16x8*)(Qh + qrow*64 + 32 + lg*8);

  float m_r[4], l_r[4];
  f32x4 acc_o[4] = {};
#pragma unroll
  for (int r = 0; r < 4; ++r){ m_r[r] = -INFINITY; l_r[r] = 0.f; }

  for (int kt = 0; kt < 32; ++kt){
    int k0 = kt * 64;
    // --- S = Q K^T ---
    f32x4 s[4];
#pragma unroll
    for (int n = 0; n < 4; ++n){
      const unsigned short* kr = Kh + (k0 + n*16 + lr) * 64 + lg*8;
      s16x8 kf0 = *(const s16x8*)(kr);
      s16x8 kf1 = *(const s16x8*)(kr + 32);
      f32x4 a = {};
      a = __builtin_amdgcn_mfma_f32_16x16x32_bf16(qf0, kf0, a, 0, 0, 0);
      a = __builtin_amdgcn_mfma_f32_16x16x32_bf16(qf1, kf1, a, 0, 0, 0);
      s[n] = a;
    }
    // --- scale + mask + rowmax ---
    float sv[4][4];
    float rm[4] = {-INFINITY, -INFINITY, -INFINITY, -INFINITY};
#pragma unroll
    for (int n = 0; n < 4; ++n){
      bool msk = mrow[k0 + n*16 + lr] != 0;
#pragma unroll
      for (int r = 0; r < 4; ++r){
        float v = s[n][r] * 0.125f;
        if (msk) v = -1e9f;
        sv[n][r] = v;
        rm[r] = fmaxf(rm[r], v);
      }
    }
#pragma unroll
    for (int r = 0; r < 4; ++r){
      float t = rm[r];
      t = fmaxf(t, __shfl_xor(t, 1));
      t = fmaxf(t, __shfl_xor(t, 2));
      t = fmaxf(t, __shfl_xor(t, 4));
      t = fmaxf(t, __shfl_xor(t, 8));
      rm[r] = t;
    }
    // --- online softmax update ---
    float alpha[4];
#pragma unroll
    for (int r = 0; r < 4; ++r){
      float mn = fmaxf(m_r[r], rm[r]);
      alpha[r] = (m_r[r] > -1e30f) ? __expf(m_r[r] - mn) : 0.f;
      m_r[r] = mn;
    }
    float p[4][4];
    float rs[4] = {0.f, 0.f, 0.f, 0.f};
#pragma unroll
    for (int n = 0; n < 4; ++n)
#pragma unroll
      for (int r = 0; r < 4; ++r){
        float pv = __expf(sv[n][r] - m_r[r]);
        p[n][r] = pv;
        rs[r] += pv;
      }
#pragma unroll
    for (int r = 0; r < 4; ++r){
      float t = rs[r];
      t += __shfl_xor(t, 1);
      t += __shfl_xor(t, 2);
      t += __shfl_xor(t, 4);
      t += __shfl_xor(t, 8);
      l_r[r] = l_r[r] * alpha[r] + t;
    }
#pragma unroll
    for (int nd = 0; nd < 4; ++nd)
#pragma unroll
      for (int r = 0; r < 4; ++r)
        acc_o[nd][r] *= alpha[r];
    // --- P -> LDS (re-layout C->A frag), same wave so no barrier needed ---
#pragma unroll
    for (int n = 0; n < 4; ++n)
#pragma unroll
      for (int r = 0; r < 4; ++r)
        plds[w][lg*4 + r][n*16 + lr] = f2b(p[n][r]);
    s16x8 pf0 = *(const s16x8*)&plds[w][lr][lg*8];
    s16x8 pf1 = *(const s16x8*)&plds[w][lr][32 + lg*8];
    // --- O += P V ---
#pragma unroll
    for (int nd = 0; nd < 4; ++nd){
      const unsigned short* vr = Vth + (nd*16 + lr) * 2048 + k0 + lg*8;
      s16x8 vf0 = *(const s16x8*)(vr);
      s16x8 vf1 = *(const s16x8*)(vr + 32);
      acc_o[nd] = __builtin_amdgcn_mfma_f32_16x16x32_bf16(pf0, vf0, acc_o[nd], 0, 0, 0);
      acc_o[nd] = __builtin_amdgcn_mfma_f32_16x16x32_bf16(pf1, vf1, acc_o[nd], 0, 0, 0);
    }
  }
  // --- normalize + write attnOut[b*2048+t][64h + d] ---
#pragma unroll
  for (int r = 0; r < 4; ++r){
    float inv = (l_r[r] > 0.f) ? 1.f / l_r[r] : 0.f;
    int t = qt*64 + w*16 + lg*4 + r;
#pragma unroll
    for (int nd = 0; nd < 4; ++nd){
      float v = acc_o[nd][r] * inv;
      attnOut[(size_t)(b*2048 + t) * 512 + h*64 + nd*16 + lr] = f2b(v);
    }
  }
}

extern "C" void kernel_launch(void* const* d_in, const int* in_sizes, int n_in,
                              void* d_out, int out_size, void* d_ws, size_t ws_size,
                              hipStream_t stream) {
  const float* q  = (const float*)d_in[0];
  const float* k  = (const float*)d_in[1];
  const float* v  = (const float*)d_in[2];
  const unsigned char* mask = (const unsigned char*)d_in[3];
  const float* Wq = (const float*)d_in[4];
  const float* Wk = (const float*)d_in[5];
  const float* Wv = (const float*)d_in[6];
  const float* Wm = (const float*)d_in[7];
  const float* bq = (const float*)d_in[8];
  const float* bk = (const float*)d_in[9];
  const float* bv = (const float*)d_in[10];
  const float* bm = (const float*)d_in[11];

  unsigned short* ws = (unsigned short*)d_ws;
  // ws layout (elements)
  const size_t QB  = 0;
  const size_t KB  = 2097152;
  const size_t VB  = 4194304;
  const size_t WQB = 6291456;
  const size_t WKB = 6553600;
  const size_t WVB = 6815744;
  const size_t WMB = 7077888;
  const size_t PQ  = 7340032;
  const size_t PK  = 9437184;
  const size_t PV  = 11534336;
  const size_t VT  = 13631488;
  const size_t AO  = 15728640;

  // convert inputs + weights to bf16
  cvt_f32_bf16<<<2048, 256, 0, stream>>>(q,  ws + QB,  2097152);
  cvt_f32_bf16<<<2048, 256, 0, stream>>>(k,  ws + KB,  2097152);
  cvt_f32_bf16<<<2048, 256, 0, stream>>>(v,  ws + VB,  2097152);
  cvt_f32_bf16<<<256, 256, 0, stream>>>(Wq, ws + WQB, 262144);
  cvt_f32_bf16<<<256, 256, 0, stream>>>(Wk, ws + WKB, 262144);
  cvt_f32_bf16<<<256, 256, 0, stream>>>(Wv, ws + WVB, 262144);
  cvt_f32_bf16<<<256, 256, 0, stream>>>(Wm, ws + WMB, 262144);

  // projections
  gemm_bt<0><<<dim3(64, 8), 256, 0, stream>>>(ws + QB, ws + WQB, bq, ws + PQ);
  gemm_bt<0><<<dim3(64, 8), 256, 0, stream>>>(ws + KB, ws + WKB, bk, ws + PK);
  gemm_bt<0><<<dim3(64, 8), 256, 0, stream>>>(ws + VB, ws + WVB, bv, ws + PV);

  // V transpose per head
  vtrans<<<dim3(32, 16), 256, 0, stream>>>(ws + PV, ws + VT);

  // flash attention
  flash<<<dim3(32, 16), 256, 0, stream>>>(ws + PQ, ws + PK, ws + VT, mask, ws + AO);

  // output projection (fp32 out)
  gemm_bt<1><<<dim3(64, 8), 256, 0, stream>>>(ws + AO, ws + WMB, bm, (float*)d_out);
}